// Round 3
// baseline (135.035 us; speedup 1.0000x reference)
//
#include <hip/hip_runtime.h>

// Fused kernelized attention w/ Toeplitz topological mask, MI355X gfx950.
// B=8 H=12 L=577 (24x24 grid + CLS) D=64, fp32 I/O (runtime-probed vs bf16).
//
// out[b,q,h,:] = sum_k p(q,k) v[k,:] / sum_k p(q,k)
//   p = (relu(q)/8+eps)·(relu(k)+eps) * |mask(h,q,k)| + eps
//
// R3 structure: GEMM1 computed TRANSPOSED (S^T = K·Q^T, operand swap) so each
// lane holds 4 k-consecutive P values for fixed q -> packed b64 writes into a
// WAVE-PRIVATE s_p tile (no barrier; same-wave LDS RAW ordered by lgkmcnt).
// q-tile 64 -> 960 blocks, all resident at 4 blocks/CU. XCD-swizzled grid.

#define Lq 577
#define NH 12
#define NB 8
#define DD 64
#define PAR 2304
#define EPSf 1e-8f

typedef __attribute__((ext_vector_type(4))) float f32x4;
typedef __attribute__((ext_vector_type(8))) short s16x8;

__device__ __forceinline__ float bflo(unsigned int u) {
    return __builtin_bit_cast(float, u << 16);
}
__device__ __forceinline__ float bfhi(unsigned int u) {
    return __builtin_bit_cast(float, u & 0xffff0000u);
}
// float -> bf16 round-to-nearest-even
__device__ __forceinline__ unsigned int f2bf(float f) {
    unsigned int x = __builtin_bit_cast(unsigned int, f);
    return (x + 0x7fffu + ((x >> 16) & 1u)) >> 16;
}
__device__ __forceinline__ int imin(int a, int b) { return a < b ? a : b; }
__device__ __forceinline__ int imax(int a, int b) { return a > b ? a : b; }

// 8 consecutive elements -> float, dtype-templated
template <bool F32>
__device__ __forceinline__ void load8f(const void* G, size_t eidx, float* o) {
    if constexpr (F32) {
        const float* p = (const float*)G + eidx;
        float4 a = *(const float4*)p;
        float4 b = *(const float4*)(p + 4);
        o[0] = a.x; o[1] = a.y; o[2] = a.z; o[3] = a.w;
        o[4] = b.x; o[5] = b.y; o[6] = b.z; o[7] = b.w;
    } else {
        const unsigned short* p = (const unsigned short*)G + eidx;
        uint4 a = *(const uint4*)p;
        unsigned int u[4] = {a.x, a.y, a.z, a.w};
#pragma unroll
        for (int j = 0; j < 4; ++j) {
            o[2 * j]     = bflo(u[j]);
            o[2 * j + 1] = bfhi(u[j]);
        }
    }
}

template <bool F32>
__device__ void attn_body(const void* __restrict__ Qg, const void* __restrict__ Kg,
                          const void* __restrict__ Vg, const void* __restrict__ Tg,
                          void* __restrict__ Og,
                          float* s_par, unsigned short* s_k,
                          unsigned short* s_vt, unsigned short* s_p_all) {
    const int tid  = threadIdx.x;
    const int w    = tid >> 6;
    const int lane = tid & 63;
    const int g    = lane >> 4;   // quad
    const int lm   = lane & 15;

    // XCD swizzle: blocks sharing (b,h) are 96 apart (96 % 8 == 0 -> same XCD)
    const int bid = blockIdx.x;
    const int qt  = bid / 96;     // q tile (64 rows), 0..9
    const int bh  = bid - qt * 96;
    const int h   = bh % NH;
    const int b   = bh / NH;

    unsigned short* s_pw = s_p_all + w * 16 * 72;   // wave-private P tile [16q][72]

    // |topological params| -> LDS (abs + NaN scrub folded in)
    for (int i = tid; i < PAR; i += 256) {
        float m = F32 ? ((const float*)Tg)[h * PAR + i]
                      : bflo((unsigned int)((const unsigned short*)Tg)[h * PAR + i]);
        m = fabsf(m);
        s_par[i] = (m == m) ? m : 0.0f;
    }

    const int q0w = qt * 64 + w * 16;   // wave's first q row

    // ---- Q B-frags in registers: lane holds Q[q0w+lm][ds*32+g*8+j]
    const int q  = q0w + lm;
    const int qc = imin(q, Lq - 1);   // clamp: garbage rows never stored
    s16x8 a_q[2];
    {
        size_t rbase = ((size_t)((b * Lq + qc) * NH + h)) * DD;
#pragma unroll
        for (int ds = 0; ds < 2; ++ds) {
            float f[8];
            load8f<F32>(Qg, rbase + ds * 32 + g * 8, f);
            s16x8 a;
#pragma unroll
            for (int j = 0; j < 8; ++j) {
                float v = fmaf(fmaxf(f[j], 0.0f), 0.125f, EPSf);  // relu/8+eps (NaN->eps)
                a[j] = (short)f2bf(v);
            }
            a_q[ds] = a;
        }
    }

    // ---- per-lane mask-row constants (q = lm position of S^T columns)
    const bool qz = (q == 0);
    const int  qq = imax(qc - 1, 0);
    const int  qi = (qq * 2731) >> 16;          // floor(qq/24), qq<639
    const int  cq = qq + 24 * qi + 1176;        // qi*48+qj+1176

    f32x4 o_acc[4] = {};   // [df] fp32 C-frags, rows q_local=g*4+r, cols d=df*16+lm
    float rs = 0.0f;       // per-lane partial row sum for q (this quad's k subset)

    // V staging assignment: lane handles k-pair (k0,k0+1) x 8 d's
    const int k0v  = 2 * (tid & 31);
    const int dchv = (tid >> 5) * 8;

    for (int kb = 0; kb < Lq; kb += 64) {
        __syncthreads();  // prev GEMM1/GEMM2 done reading s_k/s_vt

        // ---- stage K (relu+eps, bf16): lane = k-row, wave = 16-d chunk
        {
            int kgc = imin(kb + lane, Lq - 1);
            size_t base = ((size_t)((b * Lq + kgc) * NH + h)) * DD + w * 16;
            float kr[16];
            load8f<F32>(Kg, base,     kr);
            load8f<F32>(Kg, base + 8, kr + 8);
            unsigned int kt[8];
#pragma unroll
            for (int j = 0; j < 8; ++j) {
                float f0 = fmaxf(kr[2 * j], 0.0f) + EPSf;       // NaN -> eps
                float f1 = fmaxf(kr[2 * j + 1], 0.0f) + EPSf;
                kt[j] = f2bf(f0) | (f2bf(f1) << 16);
            }
            *(uint4*)&s_k[lane * 72 + w * 16]     = make_uint4(kt[0], kt[1], kt[2], kt[3]);
            *(uint4*)&s_k[lane * 72 + w * 16 + 8] = make_uint4(kt[4], kt[5], kt[6], kt[7]);
        }
        // ---- stage V^T pair-packed: 8 b32 writes, each = (V[k0][d], V[k0+1][d])
        {
            int kg0 = imin(kb + k0v,     Lq - 1);
            int kg1 = imin(kb + k0v + 1, Lq - 1);
            size_t b0 = ((size_t)((b * Lq + kg0) * NH + h)) * DD + dchv;
            size_t b1 = ((size_t)((b * Lq + kg1) * NH + h)) * DD + dchv;
            float v0[8], v1[8];
            load8f<F32>(Vg, b0, v0);
            load8f<F32>(Vg, b1, v1);
#pragma unroll
            for (int j = 0; j < 8; ++j) {
                float a0 = v0[j], a1 = v1[j];
                a0 = (a0 == a0) ? a0 : 0.0f;                    // scrub NaN
                a1 = (a1 == a1) ? a1 : 0.0f;
                *(unsigned int*)&s_vt[(dchv + j) * 72 + k0v] =
                    f2bf(a0) | (f2bf(a1) << 16);
            }
        }
        __syncthreads();

        // ---- GEMM1 (transposed): S^T[64k x 16q] = K · Q^T
        f32x4 sf[4];
#pragma unroll
        for (int cf = 0; cf < 4; ++cf) {
            s16x8 kf0 = *(const s16x8*)&s_k[(cf * 16 + lm) * 72 + g * 8];
            s16x8 kf1 = *(const s16x8*)&s_k[(cf * 16 + lm) * 72 + 32 + g * 8];
            f32x4 acc = {};
            acc = __builtin_amdgcn_mfma_f32_16x16x32_bf16(kf0, a_q[0], acc, 0, 0, 0);
            acc = __builtin_amdgcn_mfma_f32_16x16x32_bf16(kf1, a_q[1], acc, 0, 0, 0);
            sf[cf] = acc;   // reg r: k_local = cf*16 + g*4 + r, q = q0w + lm
        }

        // ---- mask * |M| + eps, row-sum, pack 4 k-consecutive P -> b64 LDS write
#pragma unroll
        for (int cf = 0; cf < 4; ++cf) {
            float p[4];
#pragma unroll
            for (int r = 0; r < 4; ++r) {
                int  k  = kb + cf * 16 + g * 4 + r;
                bool kv = k < Lq;
                bool um = (k > 0) && kv && !qz;
                int  kk = imax(k - 1, 0);
                int  ki = (kk * 2731) >> 16;        // floor(kk/24)
                int  kl = kk + 24 * ki;             // ki*48 + kj
                int  idx = um ? (cq - kl) : 0;      // in [49,2303] when um
                float mm = um ? s_par[idx] : (kv ? 1.0f : 0.0f);
                float s  = fmaxf(sf[cf][r], 0.0f);  // s>=0; scrubs NaN
                float pp = fmaf(s, mm, kv ? EPSf : 0.0f);   // 0 for k>=L
                rs += pp;
                p[r] = pp;
            }
            unsigned int d0 = f2bf(p[0]) | (f2bf(p[1]) << 16);
            unsigned int d1 = f2bf(p[2]) | (f2bf(p[3]) << 16);
            // row q=lm, cols cf*16+g*4..+3 ; byte offset 8-aligned (144*lm+32*cf+8*g)
            *(uint2*)&s_pw[lm * 72 + cf * 16 + g * 4] = make_uint2(d0, d1);
        }
        // no barrier: s_pw is wave-private; lgkmcnt orders write->read

        // ---- GEMM2: O[16q x 64d] += P · V
#pragma unroll
        for (int ks = 0; ks < 2; ++ks) {
            s16x8 pa = *(const s16x8*)&s_pw[lm * 72 + ks * 32 + g * 8];
#pragma unroll
            for (int df = 0; df < 4; ++df) {
                s16x8 vb = *(const s16x8*)&s_vt[(df * 16 + lm) * 72 + ks * 32 + g * 8];
                o_acc[df] = __builtin_amdgcn_mfma_f32_16x16x32_bf16(pa, vb, o_acc[df], 0, 0, 0);
            }
        }
    }

    // ---- total row sum for q=lm: combine the 4 quad partials
    float tot = rs;
    tot += __shfl_xor(tot, 16, 64);
    tot += __shfl_xor(tot, 32, 64);
    float inv = (tot > 0.0f) ? 1.0f / tot : 0.0f;

    // ---- epilogue: rows q = q0w + g*4 + r; fetch inv from lane (g*4+r)
#pragma unroll
    for (int r = 0; r < 4; ++r) {
        int   qrow  = q0w + g * 4 + r;
        float inv_r = __shfl(inv, g * 4 + r, 64);
        if (qrow < Lq) {
            size_t base = ((size_t)((b * Lq + qrow) * NH + h)) * DD;
#pragma unroll
            for (int df = 0; df < 4; ++df) {
                float val = o_acc[df][r] * inv_r;
                val = fminf(fmaxf(val, -1e30f), 1e30f);
                if constexpr (F32)
                    ((float*)Og)[base + df * 16 + lm] = val;
                else
                    ((unsigned short*)Og)[base + df * 16 + lm] = (unsigned short)f2bf(val);
            }
        }
    }
}

__global__ __launch_bounds__(256, 4)
void fused_topo_attn(const void* __restrict__ Qg, const void* __restrict__ Kg,
                     const void* __restrict__ Vg, const void* __restrict__ Tg,
                     void* __restrict__ Og) {
    // 36,864 B total -> 4 blocks/CU
    __shared__ __align__(16) float          s_par[PAR];          // 9216 B
    __shared__ __align__(16) unsigned short s_k[64 * 72];        // 9216 B
    __shared__ __align__(16) unsigned short s_vt[64 * 72];       // 9216 B
    __shared__ __align__(16) unsigned short s_p[4 * 16 * 72];    // 9216 B

    // dtype probe: fp32 N(0,1) lands in (2^-12, 64); bf16-pair reinterpretation
    // lands at ~2^+-100 / denormal. Uniform, deterministic, graph-safe.
    float x = fabsf(((const float*)Qg)[threadIdx.x]);
    int n = __syncthreads_count(x > 2.44140625e-4f && x < 64.0f);

    if (n >= 128)
        attn_body<true>(Qg, Kg, Vg, Tg, Og, s_par, s_k, s_vt, s_p);
    else
        attn_body<false>(Qg, Kg, Vg, Tg, Og, s_par, s_k, s_vt, s_p);
}

extern "C" void kernel_launch(void* const* d_in, const int* in_sizes, int n_in,
                              void* d_out, int out_size, void* d_ws, size_t ws_size,
                              hipStream_t stream) {
    (void)in_sizes; (void)n_in; (void)out_size; (void)d_ws; (void)ws_size;
    dim3 grid(960);   // 10 q-tiles x 96 (b,h), swizzled: same (b,h) -> same XCD
    fused_topo_attn<<<grid, 256, 0, stream>>>(d_in[0], d_in[1], d_in[2], d_in[3], d_out);
}

// Round 4
// 123.388 us; speedup vs baseline: 1.0944x; 1.0944x over previous
//
#include <hip/hip_runtime.h>

// Fused kernelized attention w/ Toeplitz topological mask, MI355X gfx950.
// B=8 H=12 L=577 (24x24 grid + CLS) D=64, fp32 I/O (runtime-probed vs bf16).
//
// out[b,q,h,:] = sum_k p(q,k) v[k,:] / sum_k p(q,k)
//   p = (relu(q)/8+eps)·(relu(k)+eps) * |mask(h,q,k)| + eps
//
// R4: three pre-kernels write d_ws:  K'=bf16(relu(K)+eps) [b,k,h,d];
// V^T bf16 [b,h,d,640] (zeros past k=576); M=|mask| bf16 [h,q,640]
// (CLS rows/cols = 1, pad = 0 baked in). Main kernel stages K'/V^T/M via
// global_load_lds_dwordx4 with a 16B XOR swizzle (chunk ^= row&7) on the
// per-lane global source so unpadded LDS rows still give conflict-free b128
// fragment reads. P stays in a wave-private padded tile (no barrier).

#define Lq 577
#define NH 12
#define NB 8
#define DD 64
#define PAR 2304
#define EPSf 1e-8f

// workspace layout (bytes)
#define VT_OFF 7090176ull     // K' = 3,545,088 elem * 2B
#define MM_OFF 14954496ull    // + V^T = 8*12*64*640*2 = 7,864,320
                              // + M   = 12*577*640*2  = 8,862,720  (total 23.8 MB)

typedef __attribute__((ext_vector_type(4))) float f32x4;
typedef __attribute__((ext_vector_type(8))) short s16x8;

__device__ __forceinline__ float bflo(unsigned int u) {
    return __builtin_bit_cast(float, u << 16);
}
__device__ __forceinline__ float bfhi(unsigned int u) {
    return __builtin_bit_cast(float, u & 0xffff0000u);
}
// float -> bf16 round-to-nearest-even
__device__ __forceinline__ unsigned int f2bf(float f) {
    unsigned int x = __builtin_bit_cast(unsigned int, f);
    return (x + 0x7fffu + ((x >> 16) & 1u)) >> 16;
}
__device__ __forceinline__ int imin(int a, int b) { return a < b ? a : b; }

// async global->LDS, 16B per lane; lds dest = wave-uniform base + lane*16
__device__ __forceinline__ void gload_lds16(const unsigned short* g, unsigned short* l) {
    __builtin_amdgcn_global_load_lds(
        (const __attribute__((address_space(1))) unsigned int*)g,
        (__attribute__((address_space(3))) unsigned int*)l, 16, 0, 0);
}

// per-wave dtype probe: fp32 N(0,1) lands in (2^-12, 64); bf16-pair
// reinterpretation lands at ~2^+-100 / denormal. Works for partial waves.
__device__ __forceinline__ bool probe_f32(const void* Qg) {
    float x = fabsf(((const float*)Qg)[threadIdx.x]);
    unsigned long long hit = __ballot(x > 2.44140625e-4f && x < 64.0f);
    unsigned long long act = __ballot(1);
    return 2 * __popcll(hit) >= __popcll(act);
}

// 8 consecutive elements -> float, dtype-templated
template <bool F32>
__device__ __forceinline__ void load8f(const void* G, size_t eidx, float* o) {
    if constexpr (F32) {
        const float* p = (const float*)G + eidx;
        float4 a = *(const float4*)p;
        float4 b = *(const float4*)(p + 4);
        o[0] = a.x; o[1] = a.y; o[2] = a.z; o[3] = a.w;
        o[4] = b.x; o[5] = b.y; o[6] = b.z; o[7] = b.w;
    } else {
        const unsigned short* p = (const unsigned short*)G + eidx;
        uint4 a = *(const uint4*)p;
        unsigned int u[4] = {a.x, a.y, a.z, a.w};
#pragma unroll
        for (int j = 0; j < 4; ++j) {
            o[2 * j]     = bflo(u[j]);
            o[2 * j + 1] = bfhi(u[j]);
        }
    }
}

// ---------------- pre-kernel 1: K' = bf16(relu(K)+eps), layout [b,k,h,d]
template <bool F32>
__device__ void prep_k_body(const void* Kg, unsigned short* Kp) {
    size_t i8 = ((size_t)blockIdx.x * 256 + threadIdx.x) * 8;   // 1731*2048 = 3,545,088
    float f[8];
    load8f<F32>(Kg, i8, f);
    unsigned int o[4];
#pragma unroll
    for (int j = 0; j < 4; ++j) {
        unsigned int lo = f2bf(fmaxf(f[2 * j], 0.0f) + EPSf);
        unsigned int hi = f2bf(fmaxf(f[2 * j + 1], 0.0f) + EPSf);
        o[j] = lo | (hi << 16);
    }
    *(uint4*)(Kp + i8) = make_uint4(o[0], o[1], o[2], o[3]);
}
__global__ __launch_bounds__(256)
void prep_k(const void* __restrict__ Qg, const void* __restrict__ Kg,
            unsigned short* __restrict__ Kp) {
    if (probe_f32(Qg)) prep_k_body<true>(Kg, Kp);
    else               prep_k_body<false>(Kg, Kp);
}

// ---------------- pre-kernel 2: V^T bf16 [b,h,d,640], zeros past k=576
template <bool F32>
__device__ void prep_vt_body(const void* Vg, unsigned short* Vt, unsigned short* s) {
    const int t  = threadIdx.x;
    const int kt = blockIdx.x, h = blockIdx.y, b = blockIdx.z;
    {
        int kl  = t >> 2;              // 0..63
        int dch = (t & 3) * 16;
        int k   = kt * 64 + kl;
        unsigned int pk[8] = {};
        if (k <= 576) {
            float f[16];
            size_t base = ((size_t)((b * Lq + k) * NH + h)) * DD + dch;
            load8f<F32>(Vg, base, f);
            load8f<F32>(Vg, base + 8, f + 8);
#pragma unroll
            for (int j = 0; j < 8; ++j)
                pk[j] = f2bf(f[2 * j]) | (f2bf(f[2 * j + 1]) << 16);
        }
#pragma unroll
        for (int j = 0; j < 8; ++j)
            *(unsigned int*)&s[kl * 72 + dch + 2 * j] = pk[j];
    }
    __syncthreads();
    {
        int d   = t >> 2;
        int kch = (t & 3) * 16;
        unsigned int o[8];
#pragma unroll
        for (int j = 0; j < 8; ++j) {
            unsigned short v0 = s[(kch + 2 * j) * 72 + d];
            unsigned short v1 = s[(kch + 2 * j + 1) * 72 + d];
            o[j] = (unsigned int)v0 | ((unsigned int)v1 << 16);
        }
        size_t base = ((size_t)((b * NH + h) * 64 + d)) * 640 + kt * 64 + kch;
        *(uint4*)(Vt + base)     = make_uint4(o[0], o[1], o[2], o[3]);
        *(uint4*)(Vt + base + 8) = make_uint4(o[4], o[5], o[6], o[7]);
    }
}
__global__ __launch_bounds__(256)
void prep_vt(const void* __restrict__ Qg, const void* __restrict__ Vg,
             unsigned short* __restrict__ Vt) {
    __shared__ unsigned short s[64 * 72];
    if (probe_f32(Qg)) prep_vt_body<true>(Vg, Vt, s);
    else               prep_vt_body<false>(Vg, Vt, s);
}

// ---------------- pre-kernel 3: M = |toeplitz mask| bf16 [h,q,640]
template <bool F32>
__device__ void prep_mask_body(const void* Tg, unsigned short* Mm) {
    const int q = blockIdx.x, h = blockIdx.y;
    const int k0 = threadIdx.x * 8;           // 80 threads * 8 = 640
    int cq = 0;
    if (q > 0) {
        int qq = q - 1;
        int qi = (qq * 2731) >> 16;           // floor(qq/24)
        cq = qq + 24 * qi + 1176;
    }
    unsigned int o[4];
#pragma unroll
    for (int j = 0; j < 4; ++j) {
        unsigned int hv[2];
#pragma unroll
        for (int e = 0; e < 2; ++e) {
            int k = k0 + 2 * j + e;
            float m;
            if (k > 576) m = 0.0f;
            else if (k == 0 || q == 0) m = 1.0f;
            else {
                int kk = k - 1;
                int ki = (kk * 2731) >> 16;
                int idx = cq - (kk + 24 * ki);
                float pv = F32 ? ((const float*)Tg)[h * PAR + idx]
                               : bflo((unsigned int)((const unsigned short*)Tg)[h * PAR + idx]);
                m = fabsf(pv);
                m = (m == m) ? m : 0.0f;
            }
            hv[e] = f2bf(m);
        }
        o[j] = hv[0] | (hv[1] << 16);
    }
    *(uint4*)(Mm + (size_t)(h * Lq + q) * 640 + k0) = make_uint4(o[0], o[1], o[2], o[3]);
}
__global__ __launch_bounds__(128)
void prep_mask(const void* __restrict__ Qg, const void* __restrict__ Tg,
               unsigned short* __restrict__ Mm) {
    if (probe_f32(Qg)) prep_mask_body<true>(Tg, Mm);
    else               prep_mask_body<false>(Tg, Mm);
}

// ---------------- main kernel
template <bool F32>
__device__ void attn_body(const void* __restrict__ Qg,
                          const unsigned short* __restrict__ Kp,
                          const unsigned short* __restrict__ Vt,
                          const unsigned short* __restrict__ Mm,
                          void* __restrict__ Og,
                          unsigned short* s_k, unsigned short* s_vt,
                          unsigned short* s_m, unsigned short* s_p_all) {
    const int tid  = threadIdx.x;
    const int w    = tid >> 6;
    const int lane = tid & 63;
    const int g    = lane >> 4;   // quad
    const int lm   = lane & 15;

    // XCD swizzle: blocks sharing (b,h) are 96 apart (96 % 8 == 0 -> same XCD)
    const int bid = blockIdx.x;
    const int qt  = bid / 96;     // q tile (64 rows), 0..9
    const int bh  = bid - qt * 96;
    const int h   = bh % NH;
    const int b   = bh / NH;

    unsigned short* s_pw = s_p_all + w * 16 * 72;   // wave-private P tile [16][72]
    unsigned short* s_mw = s_m + w * 1024;          // wave-private M tile [16][64]

    const int q0w = qt * 64 + w * 16;   // wave's first q row

    // ---- Q B-frags in registers: lane holds Q[q0w+lm][ds*32+g*8+j]
    const int q  = q0w + lm;
    const int qc = imin(q, Lq - 1);
    s16x8 a_q[2];
    {
        size_t rbase = ((size_t)((b * Lq + qc) * NH + h)) * DD;
#pragma unroll
        for (int ds = 0; ds < 2; ++ds) {
            float f[8];
            load8f<F32>(Qg, rbase + ds * 32 + g * 8, f);
            s16x8 a;
#pragma unroll
            for (int j = 0; j < 8; ++j) {
                float v = fmaf(fmaxf(f[j], 0.0f), 0.125f, EPSf);  // relu/8+eps
                a[j] = (short)f2bf(v);
            }
            a_q[ds] = a;
        }
    }

    // ---- staging lane constants (XOR-swizzled source chunks)
    const int r8 = lane >> 3;          // row within 8-row group
    const int c8 = lane & 7;           // 16B chunk within row
    const int xr = (c8 ^ r8) * 8;      // logical element offset of this lane's chunk

    const unsigned short* KpBH = Kp + (size_t)b * (Lq * NH * DD) + h * DD;   // + k*768
    const unsigned short* VtL0 = Vt + ((size_t)(b * NH + h) * 64 + (w * 16 + r8)) * 640 + xr;
    const unsigned short* VtL1 = VtL0 + 8 * 640;
    const unsigned short* MmH  = Mm + (size_t)h * (Lq * 640);
    const unsigned short* MmL0 = MmH + (size_t)imin(q0w + r8, Lq - 1) * 640 + xr;
    const unsigned short* MmL1 = MmH + (size_t)imin(q0w + 8 + r8, Lq - 1) * 640 + xr;

    unsigned short* sk0 = s_k  + (w * 16) * 64;
    unsigned short* sk1 = sk0 + 8 * 64;
    unsigned short* sv0 = s_vt + (w * 16) * 64;
    unsigned short* sv1 = sv0 + 8 * 64;
    unsigned short* sm1 = s_mw + 8 * 64;

    f32x4 o_acc[4] = {};   // [df] C-frags: rows q_local=g*4+r, cols d=df*16+lm
    float rs = 0.0f;       // per-lane partial row sum for q (this quad's k subset)

    const int x7 = lm & 7;             // fragment-read swizzle key

    for (int kb = 0; kb < 640; kb += 64) {
        __syncthreads();  // prev tile's LDS reads done

        // ---- async stage K' rows, V^T rows, M rows (6 x 1KB per wave)
        int krr = kb + w * 16 + r8;
        int kr0 = imin(krr, Lq - 1);
        int kr1 = imin(krr + 8, Lq - 1);
        gload_lds16(KpBH + (size_t)kr0 * (NH * DD) + xr, sk0);
        gload_lds16(KpBH + (size_t)kr1 * (NH * DD) + xr, sk1);
        gload_lds16(VtL0 + kb, sv0);
        gload_lds16(VtL1 + kb, sv1);
        gload_lds16(MmL0 + kb, s_mw);
        gload_lds16(MmL1 + kb, sm1);
        __syncthreads();  // drains vmcnt -> LDS tiles ready

        // ---- GEMM1 (transposed): S^T[64k x 16q] = K' · Q^T
        f32x4 sf[4];
#pragma unroll
        for (int cf = 0; cf < 4; ++cf) {
            const unsigned short* skr = s_k + (cf * 16 + lm) * 64;
            int co = (g ^ x7) * 8;
            s16x8 kf0 = *(const s16x8*)(skr + co);
            s16x8 kf1 = *(const s16x8*)(skr + (co ^ 32));
            f32x4 acc = {};
            acc = __builtin_amdgcn_mfma_f32_16x16x32_bf16(kf0, a_q[0], acc, 0, 0, 0);
            acc = __builtin_amdgcn_mfma_f32_16x16x32_bf16(kf1, a_q[1], acc, 0, 0, 0);
            sf[cf] = acc;   // reg r: k_local = cf*16 + g*4 + r, q = q0w + lm
        }

        // ---- p = max(s,0)*m + eps; row-sum; pack 4 -> b64 wave-private LDS
#pragma unroll
        for (int cf = 0; cf < 4; ++cf) {
            int mo = ((cf * 2 + (g >> 1)) ^ x7) * 8 + (g & 1) * 4;
            uint2 mu = *(const uint2*)&s_mw[lm * 64 + mo];
            float m0 = bflo(mu.x), m1 = bfhi(mu.x);
            float m2 = bflo(mu.y), m3 = bfhi(mu.y);
            float p0 = fmaf(fmaxf(sf[cf][0], 0.0f), m0, EPSf);
            float p1 = fmaf(fmaxf(sf[cf][1], 0.0f), m1, EPSf);
            float p2 = fmaf(fmaxf(sf[cf][2], 0.0f), m2, EPSf);
            float p3 = fmaf(fmaxf(sf[cf][3], 0.0f), m3, EPSf);
            rs += (p0 + p1) + (p2 + p3);
            unsigned int d0 = f2bf(p0) | (f2bf(p1) << 16);
            unsigned int d1 = f2bf(p2) | (f2bf(p3) << 16);
            *(uint2*)&s_pw[lm * 72 + cf * 16 + g * 4] = make_uint2(d0, d1);
        }
        // no barrier: s_pw wave-private; lgkmcnt orders write->read

        // ---- GEMM2: O[16q x 64d] += P · V
#pragma unroll
        for (int ks = 0; ks < 2; ++ks) {
            s16x8 pa = *(const s16x8*)&s_pw[lm * 72 + ks * 32 + g * 8];
#pragma unroll
            for (int df = 0; df < 4; ++df) {
                const unsigned short* svr = s_vt + (df * 16 + lm) * 64;
                s16x8 vb = *(const s16x8*)(svr + ((ks * 4 + g) ^ x7) * 8);
                o_acc[df] = __builtin_amdgcn_mfma_f32_16x16x32_bf16(pa, vb, o_acc[df], 0, 0, 0);
            }
        }
    }
    // note: k in [577,640) contributes m=0, V^T=0 -> only +63*eps on rs (negligible)

    // ---- total row sum for q = q0w+lm: combine the 4 quad partials
    float tot = rs;
    tot += __shfl_xor(tot, 16, 64);
    tot += __shfl_xor(tot, 32, 64);
    float inv = (tot > 0.0f) ? 1.0f / tot : 0.0f;

    // ---- epilogue: rows q = q0w + g*4 + r; fetch inv from lane (g*4+r)
#pragma unroll
    for (int r = 0; r < 4; ++r) {
        int   qrow  = q0w + g * 4 + r;
        float inv_r = __shfl(inv, g * 4 + r, 64);
        if (qrow < Lq) {
            size_t base = ((size_t)((b * Lq + qrow) * NH + h)) * DD;
#pragma unroll
            for (int df = 0; df < 4; ++df) {
                float val = o_acc[df][r] * inv_r;
                if constexpr (F32)
                    ((float*)Og)[base + df * 16 + lm] = val;
                else
                    ((unsigned short*)Og)[base + df * 16 + lm] = (unsigned short)f2bf(val);
            }
        }
    }
}

__global__ __launch_bounds__(256, 4)
void fused_topo_attn(const void* __restrict__ Qg,
                     const unsigned short* __restrict__ Kp,
                     const unsigned short* __restrict__ Vt,
                     const unsigned short* __restrict__ Mm,
                     void* __restrict__ Og) {
    // 33,792 B total
    __shared__ __align__(16) unsigned short s_k[64 * 64];      // 8192 B (swizzled)
    __shared__ __align__(16) unsigned short s_vt[64 * 64];     // 8192 B (swizzled)
    __shared__ __align__(16) unsigned short s_m[4 * 16 * 64];  // 8192 B (swizzled)
    __shared__ __align__(16) unsigned short s_p[4 * 16 * 72];  // 9216 B (padded)

    if (probe_f32(Qg)) attn_body<true>(Qg, Kp, Vt, Mm, Og, s_k, s_vt, s_m, s_p);
    else               attn_body<false>(Qg, Kp, Vt, Mm, Og, s_k, s_vt, s_m, s_p);
}

extern "C" void kernel_launch(void* const* d_in, const int* in_sizes, int n_in,
                              void* d_out, int out_size, void* d_ws, size_t ws_size,
                              hipStream_t stream) {
    (void)in_sizes; (void)n_in; (void)out_size; (void)ws_size;
    unsigned short* Kp = (unsigned short*)d_ws;
    unsigned short* Vt = (unsigned short*)((char*)d_ws + VT_OFF);
    unsigned short* Mm = (unsigned short*)((char*)d_ws + MM_OFF);

    prep_k<<<1731, 256, 0, stream>>>(d_in[0], d_in[1], Kp);              // 1731*2048 = |K|
    prep_vt<<<dim3(10, NH, NB), 256, 0, stream>>>(d_in[0], d_in[2], Vt);
    prep_mask<<<dim3(Lq, NH), 80, 0, stream>>>(d_in[0], d_in[3], Mm);
    fused_topo_attn<<<960, 256, 0, stream>>>(d_in[0], Kp, Vt, Mm, d_out);
}